// Round 3
// baseline (187.900 us; speedup 1.0000x reference)
//
#include <hip/hip_runtime.h>

// GridSample1d, align_corners=True, border padding.
// inp [64,64,4096] f32, grid [64,8192] f32, out [64,64,8192] f32.
//
// R7: pipeline ACROSS tiles to overlap reads with writes machine-wide.
// R5/R6 post-mortem: bulk-synchronous blocks serialize the GPU into
// [all-DMA, no stores] -> barrier -> [all-stores] phases, so the 67 MB of
// input reads never overlaps the 134 MB of NT writes (R6's whole-GPU
// generations made this worst-case: ~29us kernel vs ~20us write floor).
//
// Structure: 512 blocks (exactly 2 resident/CU at 64 KB LDS -> ALL blocks
// resident, zero generations). Each block: one n, 8 consecutive channels,
// processed as T=4 tiles of CPB=2 rows with ping-pong LDS halves.
//   prologue: DMA tile0; grid loads + index math ONCE (shared by all 4 tiles)
//   loop t:   issue DMA(t+1) -> s_waitcnt vmcnt(8) [counted, never 0
//             mid-loop: next tile's 8 loads stay in flight across the
//             barrier] -> s_barrier -> gather+NT-store tile t -> s_barrier
//             (WAR fence: next iteration's DMA overwrites buf[t&1]).
// Raw s_barrier + sched_barrier(0) fences instead of __syncthreads()
// (which drains vmcnt(0) and would kill the pipeline).

constexpr int N_    = 64;
constexpr int C_    = 64;
constexpr int L_IN  = 4096;
constexpr int L_OUT = 8192;

constexpr int BLOCK = 256;
constexpr int CPB   = 2;                       // channel rows per tile
constexpr int T     = 4;                       // tiles per block (ping-pong)
constexpr int EPT   = L_OUT / BLOCK;           // 32 grid points per thread
constexpr int NCH   = EPT / 4;                 // 8 float4 chunks
constexpr int KSTEP = L_IN / (BLOCK * 4);      // 4 DMA chunks per row
constexpr int LPT   = CPB * KSTEP;             // 8 DMA loads/thread/tile
constexpr int NBLOCKS = N_ * C_ / (CPB * T);   // 512

typedef float f32x4 __attribute__((ext_vector_type(4)));

__global__ __launch_bounds__(BLOCK, 2) void gs1d_kernel(
    const float* __restrict__ inp, const float* __restrict__ grid,
    float* __restrict__ out)
{
    __shared__ float buf[2][CPB][L_IN];  // 64 KB ping-pong

    const int tid = threadIdx.x;
    const int bid = blockIdx.x;          // n*8 + g
    const int n   = bid >> 3;
    const int g   = bid & 7;

    // 8 consecutive channels per block: c_base = g*8; tile t = rows 2t,2t+1.
    const float* src0 = inp + ((size_t)n * C_ + (size_t)g * (CPB * T)) * L_IN;

    // Stage tile t into buf[bsel]: 8 x (256 lanes x 16 B) async DMA.
    // LDS dest semantics: wave-uniform base + lane*16 (m97/m104) -> linear.
    auto stage = [&](int bsel, int t) {
        const float* s = src0 + (size_t)t * CPB * L_IN;
#pragma unroll
        for (int r = 0; r < CPB; ++r)
#pragma unroll
            for (int k = 0; k < KSTEP; ++k) {
                int e     = (k * BLOCK + tid) * 4;          // per-lane float idx
                int lbase = (k * BLOCK + (tid & ~63)) * 4;  // wave-uniform idx
                __builtin_amdgcn_global_load_lds(
                    (const __attribute__((address_space(1))) void*)(s + r * L_IN + e),
                    (__attribute__((address_space(3))) void*)(&buf[bsel][r][lbase]),
                    16, 0, 0);
            }
    };

    stage(0, 0);  // prologue DMA, covered by the index phase below

    const float* grow = grid + (size_t)n * L_OUT;

    // Grid loads + index math ONCE per block (all 4 tiles share this n).
    int   li[EPT];
    float w1[EPT];
#pragma unroll
    for (int h = 0; h < NCH; ++h) {
        float4 gv = *reinterpret_cast<const float4*>(grow + h * (BLOCK * 4) + 4 * tid);
        const float* gp = &gv.x;
#pragma unroll
        for (int j = 0; j < 4; ++j) {
            // exact reference op order: ((g+1)*0.5)*(L-1), clip, floor
            float x = (gp[j] + 1.0f) * 0.5f * (float)(L_IN - 1);
            x = fminf(fmaxf(x, 0.0f), (float)(L_IN - 1));
            float xf = floorf(x);
            int   i0 = (int)xf;
            float w  = x - xf;
            // boundary: at i0==L-1 shift to (li=L-2, w1=1) so the
            // unconditional lerp a + w1*(b-a) stays exact.
            li[h * 4 + j] = min(i0, L_IN - 2);
            w1[h * 4 + j] = (i0 >= L_IN - 1) ? 1.0f : w;
        }
    }

    float* obase = out + ((size_t)n * C_ + (size_t)g * (CPB * T)) * L_OUT;

#pragma unroll
    for (int t = 0; t < T; ++t) {
        if (t + 1 < T) {
            stage((t + 1) & 1, t + 1);  // next tile's DMA rides across barrier
            // counted wait: tile t's 8 loads (oldest) done; tile t+1's 8 in flight
            asm volatile("s_waitcnt vmcnt(8)" ::: "memory");
        } else {
            asm volatile("s_waitcnt vmcnt(0)" ::: "memory");
        }
        __builtin_amdgcn_s_barrier();          // tile t visible to all waves
        __builtin_amdgcn_sched_barrier(0);     // pin: no ds_read hoisted above

        const float* r0 = &buf[t & 1][0][0];
        const float* r1 = &buf[t & 1][1][0];
        float* orow = obase + (size_t)t * CPB * L_OUT;

#pragma unroll
        for (int h = 0; h < NCH; ++h) {
            f32x4 o0, o1;
#pragma unroll
            for (int j = 0; j < 4; ++j) {
                int   p  = h * 4 + j;
                int   q  = li[p];
                float a0 = r0[q];        // ds_read2_b32 pair
                float b0 = r0[q + 1];
                float a1 = r1[q];
                float b1 = r1[q + 1];
                o0[j] = fmaf(w1[p], b0 - a0, a0);
                o1[j] = fmaf(w1[p], b1 - a1, a1);
            }
            __builtin_nontemporal_store(o0,
                reinterpret_cast<f32x4*>(orow + h * (BLOCK * 4) + 4 * tid));
            __builtin_nontemporal_store(o1,
                reinterpret_cast<f32x4*>(orow + L_OUT + h * (BLOCK * 4) + 4 * tid));
        }

        if (t + 1 < T) {
            // WAR fence: iteration t+1 DMAs into buf[t&1]; every wave's
            // ds_reads of it have returned (drained by data-dep into stores).
            __builtin_amdgcn_sched_barrier(0);
            __builtin_amdgcn_s_barrier();
        }
    }
}

extern "C" void kernel_launch(void* const* d_in, const int* in_sizes, int n_in,
                              void* d_out, int out_size, void* d_ws, size_t ws_size,
                              hipStream_t stream) {
    const float* inp  = (const float*)d_in[0];
    const float* grid = (const float*)d_in[1];
    float* out = (float*)d_out;
    gs1d_kernel<<<NBLOCKS, BLOCK, 0, stream>>>(inp, grid, out);
}

// Round 4
// 182.593 us; speedup vs baseline: 1.0291x; 1.0291x over previous
//
#include <hip/hip_runtime.h>

// GridSample1d, align_corners=True, border padding.
// inp [64,64,4096] f32, grid [64,8192] f32, out [64,64,8192] f32.
//
// R8: R5 structure (proven best: 4-block stagger gives natural read/write
// overlap; R6/R7 showed cutting resident blocks to 2 costs 4-7us even with
// explicit pipelining) with occupancy pushed 4 -> 5 blocks/CU:
//   - li[] packed 2 x u16 per VGPR (values <= 4094, exact): arrays 64->48
//     regs, total ~95 -> fits launch_bounds(256,5) (VGPR<=102).
//   - 5 blocks x 32 KB = exactly 160 KB LDS/CU, 20 waves/CU.
// Everything else byte-identical to R5: per-block [8-load DMA -> index
// cover phase -> __syncthreads -> LDS gather + NT float4 stores].

constexpr int N_    = 64;
constexpr int C_    = 64;
constexpr int L_IN  = 4096;
constexpr int L_OUT = 8192;

constexpr int BLOCK = 256;
constexpr int CPB   = 2;                  // channels per block
constexpr int EPT   = L_OUT / BLOCK;      // 32 grid points per thread
constexpr int NCH   = EPT / 4;            // 8 float4 chunks
constexpr int NBLOCKS = N_ * C_ / CPB;    // 2048

typedef float f32x4 __attribute__((ext_vector_type(4)));

__global__ __launch_bounds__(BLOCK, 5) void gs1d_kernel(
    const float* __restrict__ inp, const float* __restrict__ grid,
    float* __restrict__ out)
{
    __shared__ float row[CPB][L_IN];  // 32 KB

    const int tid = threadIdx.x;
    const int bid = blockIdx.x;           // n*32 + c/2
    const int n   = bid >> 5;
    const int c0  = (bid & 31) * CPB;

    // Stage CPB input rows -> LDS: 8 x (256 lanes x 16 B) async DMA.
    // LDS dest semantics: wave-uniform base + lane*16 (m97/m104) -> linear.
    const float* src = inp + (size_t)(n * C_ + c0) * L_IN;
#pragma unroll
    for (int r = 0; r < CPB; ++r) {
#pragma unroll
        for (int k = 0; k < 4; ++k) {
            int e     = (k * BLOCK + tid) * 4;          // per-lane float index
            int lbase = (k * BLOCK + (tid & ~63)) * 4;  // wave-uniform float index
            __builtin_amdgcn_global_load_lds(
                (const __attribute__((address_space(1))) void*)(src + r * L_IN + e),
                (__attribute__((address_space(3))) void*)(&row[r][lbase]),
                16, 0, 0);
        }
    }

    const float* grow = grid + (size_t)n * L_OUT;

    // Pre-barrier: all grid loads + index math in registers; this VALU phase
    // (plus the grid-load latency) covers the 32 KB DMA's in-flight time.
    // li packed 2 x u16 per reg (exact: li <= 4094 < 2^16).
    unsigned lpk[EPT / 2];
    float    w1[EPT];
#pragma unroll
    for (int h = 0; h < NCH; ++h) {
        float4 g = *reinterpret_cast<const float4*>(grow + h * (BLOCK * 4) + 4 * tid);
        const float* gp = &g.x;
#pragma unroll
        for (int j = 0; j < 4; ++j) {
            int p = h * 4 + j;
            // exact reference op order: ((g+1)*0.5)*(L-1), clip, floor
            float x = (gp[j] + 1.0f) * 0.5f * (float)(L_IN - 1);
            x = fminf(fmaxf(x, 0.0f), (float)(L_IN - 1));
            float xf = floorf(x);
            int   i0 = (int)xf;
            float w  = x - xf;
            // boundary: at i0==L-1 shift to (li=L-2, w1=1) so the
            // unconditional lerp a + w1*(b-a) stays exact.
            int   qi = min(i0, L_IN - 2);
            w1[p] = (i0 >= L_IN - 1) ? 1.0f : w;
            if ((p & 1) == 0) lpk[p >> 1]  = (unsigned)qi;
            else              lpk[p >> 1] |= (unsigned)qi << 16;
        }
    }

    __syncthreads();  // DMA latency already covered by the index phase

    float* orow = out + (size_t)(n * C_ + c0) * L_OUT;

    // Post-barrier: LDS gather + lerp for both rows off the shared indices,
    // nontemporal coalesced float4 stores (output is never re-read).
#pragma unroll
    for (int h = 0; h < NCH; ++h) {
        f32x4 o0, o1;
#pragma unroll
        for (int j = 0; j < 4; ++j) {
            int   p  = h * 4 + j;
            int   q  = (int)((lpk[p >> 1] >> (16 * (p & 1))) & 0xffffu);  // v_bfe_u32
            float a0 = row[0][q];        // ds_read2_b32 pair
            float b0 = row[0][q + 1];
            float a1 = row[1][q];        // same vaddr, offset:16384
            float b1 = row[1][q + 1];
            o0[j] = fmaf(w1[p], b0 - a0, a0);
            o1[j] = fmaf(w1[p], b1 - a1, a1);
        }
        __builtin_nontemporal_store(o0,
            reinterpret_cast<f32x4*>(orow + h * (BLOCK * 4) + 4 * tid));
        __builtin_nontemporal_store(o1,
            reinterpret_cast<f32x4*>(orow + L_OUT + h * (BLOCK * 4) + 4 * tid));
    }
}

extern "C" void kernel_launch(void* const* d_in, const int* in_sizes, int n_in,
                              void* d_out, int out_size, void* d_ws, size_t ws_size,
                              hipStream_t stream) {
    const float* inp  = (const float*)d_in[0];
    const float* grid = (const float*)d_in[1];
    float* out = (float*)d_out;
    gs1d_kernel<<<NBLOCKS, BLOCK, 0, stream>>>(inp, grid, out);
}